// Round 11
// baseline (485.786 us; speedup 1.0000x reference)
//
#include <hip/hip_runtime.h>
#include <hip/hip_bf16.h>

#define BATCH 400
#define NPATCH 196
#define DIM 384
#define RTRI 73920          // 384*385/2
#define NSUP 200
#define OUT_SCORE 0
#define OUT_ADC 125
#define OUT_CLS (125 + BATCH * RTRI)

// ws offsets in floats (total 602880 floats = 2.41 MB)
#define WS_W      0         // 400*196  (holds w^2)
#define WS_SQ     78400     // 400*384
#define WS_RSUM   232000    // 400*384 (atomic; zeroed each launch)
#define WS_RM     385600    // 400*384
#define WS_GM     539200    // 400
#define WS_QPART  539600    // 400*8 (zeroed)
#define WS_DOTS   542800    // 200*200 (atomic; zeroed)
#define WS_PNP    582800    // 40*16 (atomic; zeroed)
#define WS_AD     583440    // 200*40
#define WS_QN     591440    // 200
#define WS_PN     591640    // 40
#define WS_PROTO  591680    // 25*384
#define WS_TSM    601280    // 25*64
#define WS_TOTAL  602880

typedef __attribute__((ext_vector_type(8))) short bf16x8;
typedef __attribute__((ext_vector_type(4))) short short4v;
typedef __attribute__((ext_vector_type(4))) float f32x4;

__device__ __forceinline__ float wave_reduce(float v) {
    #pragma unroll
    for (int o = 32; o; o >>= 1) v += __shfl_down(v, o);
    return v;
}

__device__ __forceinline__ unsigned short f2bf(float f) {
    unsigned int x = __float_as_uint(f);
    x += 0x7FFFu + ((x >> 16) & 1u);    // RNE
    return (unsigned short)(x >> 16);
}

__global__ void k_zero(float* __restrict__ p, int n) {
    int i = blockIdx.x * 256 + threadIdx.x;
    if (i < n) p[i] = 0.f;
}

// k1: cosine weights w (stored squared), cls fp32 copy, sq[d] = diag of scaled Gram
__global__ __launch_bounds__(384) void k_prep(const float* __restrict__ lsn,
                                              float* __restrict__ ws,
                                              float* __restrict__ out) {
    int b = blockIdx.x, tid = threadIdx.x;
    __shared__ float clsL[DIM];
    __shared__ float wL[NPATCH];
    __shared__ float red[6];
    const float* base = lsn + (size_t)b * 197 * DIM;
    float c = base[tid];
    clsL[tid] = c;
    out[OUT_CLS + (size_t)b * DIM + tid] = c;
    float s = wave_reduce(c * c);
    int lane = tid & 63, wv = tid >> 6;
    if (!lane) red[wv] = s;
    __syncthreads();
    float clsn = fmaxf(sqrtf(red[0]+red[1]+red[2]+red[3]+red[4]+red[5]), 1e-8f);
    const float* patch = base + DIM;
    for (int p = wv; p < NPATCH; p += 6) {
        const float* pr = patch + p * DIM;
        float dot = 0.f, nsq = 0.f;
        #pragma unroll
        for (int t = 0; t < 6; t++) {
            float v = pr[lane + 64 * t];
            float cl = clsL[lane + 64 * t];
            dot = fmaf(v, cl, dot);
            nsq = fmaf(v, v, nsq);
        }
        dot = wave_reduce(dot);
        nsq = wave_reduce(nsq);
        if (!lane) {
            float val = dot / (clsn * fmaxf(sqrtf(nsq), 1e-8f));
            wL[p] = val;
            ws[WS_W + b * NPATCH + p] = val * val;   // store w^2 (k_gram folds into B)
        }
    }
    __syncthreads();
    float acc = 0.f;
    for (int m = 0; m < NPATCH; m++) {
        float v = wL[m] * patch[m * DIM + tid];
        acc = fmaf(v, v, acc);
    }
    ws[WS_SQ + b * DIM + tid] = acc * (1.0f / 392.0f);
}

// k2: bf16 MFMA Gram, 128x128 triu blocks, 2x2 waves of 64x64.
// LDS [i][m] (LDK2=44 u16): staged via transposed dword loads (all 32 loads
// issued before any convert/write -> deep load queue), one b64 write/group.
#define LDK2 44
__global__ __launch_bounds__(256) void k_gram(const float* __restrict__ lsn,
                                              float* __restrict__ ws,
                                              float* __restrict__ out) {
    int b = blockIdx.y;
    int t = blockIdx.x;                 // 0..5 -> triu (ti,tj) of 3x3
    int ti = (t < 3) ? 0 : ((t < 5) ? 1 : 2);
    int tj = (t < 3) ? t : ((t < 5) ? t - 2 : 2);

    __shared__ __align__(16) unsigned short As[128 * LDK2];
    __shared__ __align__(16) unsigned short Bs[128 * LDK2];

    int tid = threadIdx.x;
    int lane = tid & 63, w = tid >> 6;
    int wr = w >> 1, wc = w & 1;        // 2x2 waves, each 64x64
    int dl = lane & 15, ms4 = lane >> 4;

    const float* patch = lsn + (size_t)b * 197 * DIM + DIM;
    const float* wrow = ws + WS_W + b * NPATCH;   // w^2

    f32x4 acc[4][4] = {};

    for (int k0 = 0; k0 < 224; k0 += 32) {   // 7 ksteps; m >= 196 zero-padded
        // phase 1: issue ALL 32 independent loads (transposed: 4 m's per column i)
        float v[8][4];
        #pragma unroll
        for (int it = 0; it < 8; ++it) {
            int gid = it * 256 + tid;          // 2048 tasks: arr(2) x mg(8) x iloc(128)
            int arr = gid >> 10;
            int mg = (gid >> 7) & 7;
            int iloc = gid & 127;
            int ig = (arr ? tj : ti) * 128 + iloc;
            #pragma unroll
            for (int u = 0; u < 4; ++u) {
                int m = k0 + mg * 4 + u;
                v[it][u] = (m < NPATCH) ? patch[(size_t)m * DIM + ig] : 0.f;
            }
        }
        // phase 2: scale (B side), convert, one b64 write per group
        #pragma unroll
        for (int it = 0; it < 8; ++it) {
            int gid = it * 256 + tid;
            int arr = gid >> 10;
            int mg = (gid >> 7) & 7;
            int iloc = gid & 127;
            short4v sv;
            #pragma unroll
            for (int u = 0; u < 4; ++u) {
                int m = k0 + mg * 4 + u;
                float x = v[it][u];
                if (arr && m < NPATCH) x *= wrow[m];
                sv[u] = (short)f2bf(x);
            }
            unsigned short* dst = arr ? Bs : As;
            *(short4v*)&dst[iloc * LDK2 + mg * 4] = sv;
        }
        __syncthreads();
        bf16x8 af[4], bfv[4];
        #pragma unroll
        for (int tr = 0; tr < 4; ++tr)
            af[tr] = *(const bf16x8*)&As[(wr * 64 + tr * 16 + dl) * LDK2 + ms4 * 8];
        #pragma unroll
        for (int tc = 0; tc < 4; ++tc)
            bfv[tc] = *(const bf16x8*)&Bs[(wc * 64 + tc * 16 + dl) * LDK2 + ms4 * 8];
        #pragma unroll
        for (int tr = 0; tr < 4; ++tr)
            #pragma unroll
            for (int tc = 0; tc < 4; ++tc)
                acc[tr][tc] = __builtin_amdgcn_mfma_f32_16x16x32_bf16(
                    af[tr], bfv[tc], acc[tr][tc], 0, 0, 0);
        __syncthreads();
    }

    // epilogue (verified rounds 5/8/9/10)
    const float* sqb = ws + WS_SQ + b * DIM;
    float sqi[4][4], sqj[4];
    int rbase = ti * 128 + wr * 64;
    int cbase = tj * 128 + wc * 64;
    #pragma unroll
    for (int tr = 0; tr < 4; ++tr)
        #pragma unroll
        for (int rg = 0; rg < 4; ++rg)
            sqi[tr][rg] = sqb[rbase + tr * 16 + ms4 * 4 + rg];
    #pragma unroll
    for (int tc = 0; tc < 4; ++tc)
        sqj[tc] = sqb[cbase + tc * 16 + dl];

    float* adc = out + OUT_ADC + (size_t)b * RTRI;
    float rs[4][4] = {};
    float cs[4] = {0.f, 0.f, 0.f, 0.f};
    #pragma unroll
    for (int tr = 0; tr < 4; ++tr) {
        #pragma unroll
        for (int tc = 0; tc < 4; ++tc) {
            #pragma unroll
            for (int rg = 0; rg < 4; ++rg) {
                int gi = rbase + tr * 16 + ms4 * 4 + rg;
                int gj = cbase + tc * 16 + dl;
                float dc = sqi[tr][rg] + sqj[tc] - acc[tr][tc][rg] * (1.0f / 196.0f);
                if (gi == gj) dc = 0.f;
                dc = fmaxf(dc, 0.f) + 1e-5f;
                float val = __expf(0.4f * __logf(dc));
                rs[tr][rg] += val;
                cs[tc] += val;
                if (gj >= gi)
                    adc[gi * (769 - gi) / 2 + (gj - gi)] = val;
            }
        }
    }
    #pragma unroll
    for (int tr = 0; tr < 4; ++tr)
        #pragma unroll
        for (int rg = 0; rg < 4; ++rg) {
            float v = rs[tr][rg];
            v += __shfl_xor(v, 1); v += __shfl_xor(v, 2);
            v += __shfl_xor(v, 4); v += __shfl_xor(v, 8);
            rs[tr][rg] = v;
        }
    if ((lane & 15) == 0) {
        #pragma unroll
        for (int tr = 0; tr < 4; ++tr)
            #pragma unroll
            for (int rg = 0; rg < 4; ++rg)
                atomicAdd(&ws[WS_RSUM + b * DIM + rbase + tr * 16 + ms4 * 4 + rg],
                          rs[tr][rg]);
    }
    if (ti != tj) {
        #pragma unroll
        for (int tc = 0; tc < 4; ++tc) {
            float v = cs[tc];
            v += __shfl_xor(v, 16); v += __shfl_xor(v, 32);
            cs[tc] = v;
        }
        if (lane < 16) {
            #pragma unroll
            for (int tc = 0; tc < 4; ++tc)
                atomicAdd(&ws[WS_RSUM + b * DIM + cbase + tc * 16 + lane], cs[tc]);
        }
    }
}

// k3: row means + grand mean
__global__ __launch_bounds__(384) void k_rowmean(float* __restrict__ ws) {
    int b = blockIdx.x, i = threadIdx.x;
    float s = ws[WS_RSUM + b * DIM + i];
    ws[WS_RM + b * DIM + i] = s * (1.0f / 384.0f);
    __shared__ float red[6];
    float tsum = wave_reduce(s);
    int lane = i & 63, wv = i >> 6;
    if (!lane) red[wv] = tsum;
    __syncthreads();
    if (i == 0) {
        float tot = red[0]+red[1]+red[2]+red[3]+red[4]+red[5];
        ws[WS_GM + b] = tot * (1.0f / (384.0f * 384.0f));
    }
}

// k4: in-place centering of adc (fp32), row-walk, + qnorm^2 partials
__global__ __launch_bounds__(256) void k_center(float* __restrict__ ws,
                                                float* __restrict__ out) {
    int s = blockIdx.x;       // row class i % 4 (load balance)
    int b = blockIdx.y;
    int tid = threadIdx.x;
    __shared__ float rmL[DIM];
    __shared__ float redL[4];
    const float* rm = ws + WS_RM + b * DIM;
    rmL[tid] = rm[tid];
    if (tid < DIM - 256) rmL[256 + tid] = rm[256 + tid];
    float gm = ws[WS_GM + b];
    __syncthreads();
    float* adc = out + OUT_ADC + (size_t)b * RTRI;
    float acc = 0.f;
    for (int i = s; i < DIM; i += 4) {
        int base = i * (769 - i) / 2;
        int L = DIM - i;
        float rmi = rmL[i] - gm;
        for (int off = tid; off < L; off += 256) {
            float v = adc[base + off];
            float nv = v - rmi - rmL[i + off];
            adc[base + off] = nv;
            acc = fmaf(nv, nv, acc);
        }
    }
    float t = wave_reduce(acc);
    if (!(tid & 63)) redL[tid >> 6] = t;
    __syncthreads();
    if (!tid) ws[WS_QPART + b * 8 + s] = redL[0] + redL[1] + redL[2] + redL[3];
}

// k5: DOTS[r][c] = dot(query r, ctx c) via split-K bf16 MFMA.
// grid (2,2,NS2): 104x104 output quadrant (padded 128x128), 8 waves (2x4).
#define DKD 32              // K per step
#define LDK 40              // LDS stride in bf16 (80 B: 2-way max aliasing)
#define NS2 105
#define CHB 22              // chunks per block: 105*22*32 = 73920
__global__ __launch_bounds__(512) void k_dots(const float* __restrict__ out,
                                              float* __restrict__ ws) {
    int qi = blockIdx.x, qj = blockIdx.y, ns = blockIdx.z;
    int tid = threadIdx.x;
    int lane = tid & 63, w = tid >> 6;
    int wr = w >> 2, wc = w & 3;        // 2x4 waves: 64 rows x 32 cols each
    __shared__ __align__(16) unsigned short As[128 * LDK];
    __shared__ __align__(16) unsigned short Bs[128 * LDK];
    const float* adc = out + OUT_ADC;
    int realA = (qi == 0) ? 104 : 96;
    int realB = (qj == 0) ? 104 : 96;
    const float* qb = adc + (size_t)(NSUP + qi * 104) * RTRI;
    const float* cb = adc + (size_t)(qj * 104) * RTRI;

    f32x4 acc[4][2] = {};
    for (int ck = 0; ck < CHB; ++ck) {
        int k0 = (ns * CHB + ck) * DKD;
        #pragma unroll
        for (int it = 0; it < 4; ++it) {
            int idx = tid + it * 512;
            int arr = idx >> 10;
            int r = (idx >> 3) & 127;
            int kq = (idx & 7) << 2;
            const float* src = arr ? cb : qb;
            int real = arr ? realB : realA;
            float4 v = make_float4(0.f, 0.f, 0.f, 0.f);
            if (r < real) v = *(const float4*)&src[(size_t)r * RTRI + k0 + kq];
            short4v sv;
            sv[0] = (short)f2bf(v.x); sv[1] = (short)f2bf(v.y);
            sv[2] = (short)f2bf(v.z); sv[3] = (short)f2bf(v.w);
            unsigned short* dst = arr ? Bs : As;
            *(short4v*)&dst[r * LDK + kq] = sv;
        }
        __syncthreads();
        int kb = (lane >> 4) * 8;
        bf16x8 af[4], bfv[2];
        #pragma unroll
        for (int tr = 0; tr < 4; ++tr)
            af[tr] = *(const bf16x8*)&As[(wr * 64 + tr * 16 + (lane & 15)) * LDK + kb];
        #pragma unroll
        for (int tc = 0; tc < 2; ++tc)
            bfv[tc] = *(const bf16x8*)&Bs[(wc * 32 + tc * 16 + (lane & 15)) * LDK + kb];
        #pragma unroll
        for (int tr = 0; tr < 4; ++tr)
            #pragma unroll
            for (int tc = 0; tc < 2; ++tc)
                acc[tr][tc] = __builtin_amdgcn_mfma_f32_16x16x32_bf16(
                    af[tr], bfv[tc], acc[tr][tc], 0, 0, 0);
        __syncthreads();
    }
    #pragma unroll
    for (int tr = 0; tr < 4; ++tr)
        #pragma unroll
        for (int tc = 0; tc < 2; ++tc)
            #pragma unroll
            for (int rg = 0; rg < 4; ++rg) {
                int lr = wr * 64 + tr * 16 + (lane >> 4) * 4 + rg;
                int lc = wc * 32 + tc * 16 + (lane & 15);
                if (lr < realA && lc < realB)
                    atomicAdd(&ws[WS_DOTS + (qi * 104 + lr) * 200 + (qj * 104 + lc)],
                              acc[tr][tc][rg]);
            }
}

// k5b: partial within-class ctx pair dots -> PNP[o][15], split-K
__global__ __launch_bounds__(256) void k_pn(const int* __restrict__ labels,
                                            const float* __restrict__ out,
                                            float* __restrict__ ws) {
    int o = blockIdx.x;      // c*8+f
    int sp = blockIdx.y;     // 0..7 K split
    int c = o >> 3, f = o & 7;
    int tid = threadIdx.x;
    __shared__ int rows[5];
    if (tid == 0) {
        int cnt = 0;
        for (int s = 0; s < 25; s++)
            if (labels[s] == c && cnt < 5) rows[cnt++] = s * 8 + f;
    }
    __syncthreads();
    const float* adc = out + OUT_ADC;
    float acc[15] = {};
    int lo = sp * 9240, hi = lo + 9240;
    for (int k = lo + tid; k < hi; k += 256) {
        float v[5];
        #pragma unroll
        for (int a = 0; a < 5; a++) v[a] = adc[(size_t)rows[a] * RTRI + k];
        int idx = 0;
        #pragma unroll
        for (int a = 0; a < 5; a++)
            #pragma unroll
            for (int b2 = a; b2 < 5; b2++) {
                acc[idx] = fmaf(v[a], v[b2], acc[idx]);
                idx++;
            }
    }
    __shared__ float red[15];
    if (tid < 15) red[tid] = 0.f;
    __syncthreads();
    #pragma unroll
    for (int i = 0; i < 15; i++) {
        float t = wave_reduce(acc[i]);
        if (!(tid & 63)) atomicAdd(&red[i], t);
    }
    __syncthreads();
    if (tid < 15) atomicAdd(&ws[WS_PNP + o * 16 + tid], red[tid]);
}

// k6: qn + pn finalize + ad from DOTS/PNP/QPART
__global__ __launch_bounds__(256) void k_post(const int* __restrict__ labels,
                                              float* __restrict__ ws) {
    __shared__ int mem[5][5];
    int tid = threadIdx.x;
    if (tid == 0) {
        int cnt[5] = {0,0,0,0,0};
        for (int s = 0; s < 25; s++) { int c = labels[s]; if (cnt[c] < 5) mem[c][cnt[c]++] = s; }
    }
    __syncthreads();
    for (int r = tid; r < 200; r += 256) {
        float ssum = 0.f;
        #pragma unroll
        for (int k = 0; k < 8; k++) ssum += ws[WS_QPART + (200 + r) * 8 + k];
        ws[WS_QN + r] = fmaxf(sqrtf(fmaxf(ssum, 0.f)), 1e-8f);
    }
    if (tid < 40) {
        float tot = 0.f;
        int idx = 0;
        #pragma unroll
        for (int a = 0; a < 5; a++)
            #pragma unroll
            for (int b2 = a; b2 < 5; b2++) {
                tot += ((a == b2) ? 1.f : 2.f) * ws[WS_PNP + tid * 16 + idx];
                idx++;
            }
        ws[WS_PN + tid] = fmaxf(sqrtf(fmaxf(tot, 0.f)) * 0.2f, 1e-8f);
    }
    __syncthreads();
    for (int idx = tid; idx < 8000; idx += 256) {
        int r = idx / 40, o = idx % 40;
        int c = o >> 3, f = o & 7;
        float s = 0.f;
        #pragma unroll
        for (int a = 0; a < 5; a++)
            s += ws[WS_DOTS + r * 200 + mem[c][a] * 8 + f];
        ws[WS_AD + idx] = s * 0.2f;
    }
}

// k7: proto[q] = mean_f(query cls) + mean_all(support cls)
__global__ __launch_bounds__(384) void k_proto(const float* __restrict__ lsn,
                                               float* __restrict__ ws) {
    int tid = threadIdx.x;
    float tsv = 0.f;
    for (int r = 0; r < 200; r++) tsv += lsn[(size_t)r * 197 * DIM + tid];
    tsv *= (1.0f / 200.0f);
    for (int q = 0; q < 25; q++) {
        float s = 0.f;
        #pragma unroll
        for (int f = 0; f < 8; f++) s += lsn[(size_t)(200 + q * 8 + f) * 197 * DIM + tid];
        ws[WS_PROTO + q * DIM + tid] = s * (1.0f / 8.0f) + tsv;
    }
}

// k8: tsm[q][g] = proto[q] . gen_weight[g]
__global__ __launch_bounds__(64) void k_tsm(const float* __restrict__ gw,
                                            float* __restrict__ ws) {
    int q = blockIdx.x, g = threadIdx.x;
    const float* pr = ws + WS_PROTO + q * DIM;
    const float* gr = gw + g * DIM;
    float s = 0.f;
    for (int d = 0; d < DIM; d++) s = fmaf(pr[d], gr[d], s);
    ws[WS_TSM + q * 64 + g] = s;
}

// k9: final score
__global__ __launch_bounds__(128) void k_score(const float* __restrict__ ws,
                                               float* __restrict__ out) {
    int t = threadIdx.x;
    if (t >= 125) return;
    int q = t / 5, wway = t % 5;
    float s = 0.f;
    for (int f = 0; f < 8; f++) {
        float qn = ws[WS_QN + q * 8 + f];
        for (int g = 0; g < 8; g++) {
            float ad = ws[WS_AD + (q * 8 + f) * 40 + wway * 8 + g];
            float pnv = ws[WS_PN + wway * 8 + g];
            s += (ad / (qn * pnv)) * ws[WS_TSM + q * 64 + f * 8 + g];
        }
    }
    out[OUT_SCORE + t] = s;
}

extern "C" void kernel_launch(void* const* d_in, const int* in_sizes, int n_in,
                              void* d_out, int out_size, void* d_ws, size_t ws_size,
                              hipStream_t stream) {
    const float* lsn = (const float*)d_in[0];
    const float* gw = (const float*)d_in[1];
    const int* labels = (const int*)d_in[2];
    float* ws = (float*)d_ws;
    float* out = (float*)d_out;

    {
        int n = (WS_AD - WS_RSUM);   // RSUM, RM, GM, QPART, DOTS, PNP
        k_zero<<<dim3((n + 255) / 256), dim3(256), 0, stream>>>(ws + WS_RSUM, n);
    }
    k_prep<<<dim3(BATCH), dim3(384), 0, stream>>>(lsn, ws, out);
    k_gram<<<dim3(6, BATCH), dim3(256), 0, stream>>>(lsn, ws, out);
    k_rowmean<<<dim3(BATCH), dim3(384), 0, stream>>>(ws);
    k_center<<<dim3(4, BATCH), dim3(256), 0, stream>>>(ws, out);
    k_dots<<<dim3(2, 2, NS2), dim3(512), 0, stream>>>(out, ws);
    k_pn<<<dim3(40, 8), dim3(256), 0, stream>>>(labels, out, ws);
    k_post<<<1, dim3(256), 0, stream>>>(labels, ws);
    k_proto<<<1, dim3(384), 0, stream>>>(lsn, ws);
    k_tsm<<<dim3(25), dim3(64), 0, stream>>>(gw, ws);
    k_score<<<1, dim3(128), 0, stream>>>(ws, out);
}

// Round 12
// 454.864 us; speedup vs baseline: 1.0680x; 1.0680x over previous
//
#include <hip/hip_runtime.h>
#include <hip/hip_bf16.h>

#define BATCH 400
#define NPATCH 196
#define DIM 384
#define RTRI 73920          // 384*385/2
#define NSUP 200
#define OUT_SCORE 0
#define OUT_ADC 125
#define OUT_CLS (125 + BATCH * RTRI)

// ws offsets in floats (total 602880 floats = 2.41 MB)
#define WS_W      0         // 400*196  (holds w^2)
#define WS_SQ     78400     // 400*384
#define WS_RSUM   232000    // 400*384 (atomic; zeroed each launch)
#define WS_RM     385600    // 400*384
#define WS_GM     539200    // 400
#define WS_QPART  539600    // 400*8 (zeroed)
#define WS_DOTS   542800    // 200*200 (atomic; zeroed)
#define WS_PNP    582800    // 40*16 (atomic; zeroed)
#define WS_AD     583440    // 200*40
#define WS_QN     591440    // 200
#define WS_PN     591640    // 40
#define WS_PROTO  591680    // 25*384
#define WS_TSM    601280    // 25*64
#define WS_TOTAL  602880

typedef __attribute__((ext_vector_type(8))) short bf16x8;
typedef __attribute__((ext_vector_type(4))) short short4v;
typedef __attribute__((ext_vector_type(4))) float f32x4;

__device__ __forceinline__ float wave_reduce(float v) {
    #pragma unroll
    for (int o = 32; o; o >>= 1) v += __shfl_down(v, o);
    return v;
}

__device__ __forceinline__ unsigned short f2bf(float f) {
    unsigned int x = __float_as_uint(f);
    x += 0x7FFFu + ((x >> 16) & 1u);    // RNE
    return (unsigned short)(x >> 16);
}

__global__ void k_zero(float* __restrict__ p, int n) {
    int i = blockIdx.x * 256 + threadIdx.x;
    if (i < n) p[i] = 0.f;
}

// k1: cosine weights w (stored squared), cls fp32 copy, sq[d] = diag of scaled Gram
__global__ __launch_bounds__(384) void k_prep(const float* __restrict__ lsn,
                                              float* __restrict__ ws,
                                              float* __restrict__ out) {
    int b = blockIdx.x, tid = threadIdx.x;
    __shared__ float clsL[DIM];
    __shared__ float wL[NPATCH];
    __shared__ float red[6];
    const float* base = lsn + (size_t)b * 197 * DIM;
    float c = base[tid];
    clsL[tid] = c;
    out[OUT_CLS + (size_t)b * DIM + tid] = c;
    float s = wave_reduce(c * c);
    int lane = tid & 63, wv = tid >> 6;
    if (!lane) red[wv] = s;
    __syncthreads();
    float clsn = fmaxf(sqrtf(red[0]+red[1]+red[2]+red[3]+red[4]+red[5]), 1e-8f);
    const float* patch = base + DIM;
    for (int p = wv; p < NPATCH; p += 6) {
        const float* pr = patch + p * DIM;
        float dot = 0.f, nsq = 0.f;
        #pragma unroll
        for (int t = 0; t < 6; t++) {
            float v = pr[lane + 64 * t];
            float cl = clsL[lane + 64 * t];
            dot = fmaf(v, cl, dot);
            nsq = fmaf(v, v, nsq);
        }
        dot = wave_reduce(dot);
        nsq = wave_reduce(nsq);
        if (!lane) {
            float val = dot / (clsn * fmaxf(sqrtf(nsq), 1e-8f));
            wL[p] = val;
            ws[WS_W + b * NPATCH + p] = val * val;   // store w^2 (k_gram folds into B)
        }
    }
    __syncthreads();
    float acc = 0.f;
    for (int m = 0; m < NPATCH; m++) {
        float v = wL[m] * patch[m * DIM + tid];
        acc = fmaf(v, v, acc);
    }
    ws[WS_SQ + b * DIM + tid] = acc * (1.0f / 392.0f);
}

// k2: bf16 MFMA Gram, 128x128 triu blocks, 2x2 waves of 64x64.
// Staging: float4 loads -> 4-lane butterfly transpose in regs -> b64 k-major
// LDS writes ([i][LDK2=40]); b128 frag reads; double-buffered, 1 barrier/kstep.
#define LDK2 40
__global__ __launch_bounds__(256) void k_gram(const float* __restrict__ lsn,
                                              float* __restrict__ ws,
                                              float* __restrict__ out) {
    int b = blockIdx.y;
    int t = blockIdx.x;                 // 0..5 -> triu (ti,tj) of 3x3
    int ti = (t < 3) ? 0 : ((t < 5) ? 1 : 2);
    int tj = (t < 3) ? t : ((t < 5) ? t - 2 : 2);

    __shared__ __align__(16) unsigned short sbuf[2][2][128 * LDK2];

    int tid = threadIdx.x;
    int lane = tid & 63, w = tid >> 6;
    int wr = w >> 1, wc = w & 1;        // 2x2 waves, each 64x64
    int dl = lane & 15, ms4 = lane >> 4;
    int row_st = tid & 127;             // staging i-row after butterfly

    const float* patch = lsn + (size_t)b * 197 * DIM + DIM;
    const float* wrow = ws + WS_W + b * NPATCH;   // w^2

    f32x4 acc[4][4] = {};
    float v[8][4];

    auto do_loads = [&](int k0n) {
        #pragma unroll
        for (int it = 0; it < 8; ++it) {
            int arr = it >> 2;
            int mq = (it & 3) * 2 + (tid >> 7);
            int m = k0n + mq * 4 + (tid & 3);
            int f4 = (tid & 127) >> 2;
            int ig = (arr ? tj : ti) * 128 + f4 * 4;
            if (m < NPATCH) {
                float4 tv = *(const float4*)&patch[(size_t)m * DIM + ig];
                v[it][0] = tv.x; v[it][1] = tv.y; v[it][2] = tv.z; v[it][3] = tv.w;
            } else {
                v[it][0] = 0.f; v[it][1] = 0.f; v[it][2] = 0.f; v[it][3] = 0.f;
            }
        }
    };
    auto do_writes = [&](int k0n, int nxt) {
        #pragma unroll
        for (int it = 0; it < 8; ++it) {
            int arr = it >> 2;
            int mq = (it & 3) * 2 + (tid >> 7);
            int m = k0n + mq * 4 + (tid & 3);
            float c0 = v[it][0], c1 = v[it][1], c2 = v[it][2], c3 = v[it][3];
            if (arr) {
                float w2 = (m < NPATCH) ? wrow[m] : 0.f;
                c0 *= w2; c1 *= w2; c2 *= w2; c3 *= w2;
            }
            // butterfly transpose across lane quads: result slot j = m-offset j at own column
            float t0 = __shfl_xor(c1, 1), t1 = __shfl_xor(c0, 1);
            float t2 = __shfl_xor(c3, 1), t3 = __shfl_xor(c2, 1);
            bool b1 = (lane & 1);
            float d0 = b1 ? t0 : c0;
            float d1 = b1 ? c1 : t1;
            float d2 = b1 ? t2 : c2;
            float d3 = b1 ? c3 : t3;
            float u0 = __shfl_xor(d2, 2), u1 = __shfl_xor(d3, 2);
            float u2 = __shfl_xor(d0, 2), u3 = __shfl_xor(d1, 2);
            bool b2 = (lane & 2);
            float e0 = b2 ? u0 : d0;
            float e1 = b2 ? u1 : d1;
            float e2 = b2 ? d2 : u2;
            float e3 = b2 ? d3 : u3;
            short4v sv;
            sv[0] = (short)f2bf(e0); sv[1] = (short)f2bf(e1);
            sv[2] = (short)f2bf(e2); sv[3] = (short)f2bf(e3);
            *(short4v*)&sbuf[nxt][arr][row_st * LDK2 + mq * 4] = sv;
        }
    };

    // prologue
    do_loads(0);
    do_writes(0, 0);
    __syncthreads();

    for (int ks = 0; ks < 7; ++ks) {
        int cur = ks & 1;
        if (ks < 6) do_loads((ks + 1) * 32);
        __builtin_amdgcn_sched_barrier(0);
        bf16x8 af[4], bfv[4];
        #pragma unroll
        for (int tr = 0; tr < 4; ++tr)
            af[tr] = *(const bf16x8*)&sbuf[cur][0][(wr * 64 + tr * 16 + dl) * LDK2 + ms4 * 8];
        #pragma unroll
        for (int tc = 0; tc < 4; ++tc)
            bfv[tc] = *(const bf16x8*)&sbuf[cur][1][(wc * 64 + tc * 16 + dl) * LDK2 + ms4 * 8];
        #pragma unroll
        for (int tr = 0; tr < 4; ++tr)
            #pragma unroll
            for (int tc = 0; tc < 4; ++tc)
                acc[tr][tc] = __builtin_amdgcn_mfma_f32_16x16x32_bf16(
                    af[tr], bfv[tc], acc[tr][tc], 0, 0, 0);
        if (ks < 6) {
            do_writes((ks + 1) * 32, cur ^ 1);
            __syncthreads();
        }
    }

    // epilogue (verified rounds 5/8/9/10/11)
    const float* sqb = ws + WS_SQ + b * DIM;
    float sqi[4][4], sqj[4];
    int rbase = ti * 128 + wr * 64;
    int cbase = tj * 128 + wc * 64;
    #pragma unroll
    for (int tr = 0; tr < 4; ++tr)
        #pragma unroll
        for (int rg = 0; rg < 4; ++rg)
            sqi[tr][rg] = sqb[rbase + tr * 16 + ms4 * 4 + rg];
    #pragma unroll
    for (int tc = 0; tc < 4; ++tc)
        sqj[tc] = sqb[cbase + tc * 16 + dl];

    float* adc = out + OUT_ADC + (size_t)b * RTRI;
    float rs[4][4] = {};
    float cs[4] = {0.f, 0.f, 0.f, 0.f};
    #pragma unroll
    for (int tr = 0; tr < 4; ++tr) {
        #pragma unroll
        for (int tc = 0; tc < 4; ++tc) {
            #pragma unroll
            for (int rg = 0; rg < 4; ++rg) {
                int gi = rbase + tr * 16 + ms4 * 4 + rg;
                int gj = cbase + tc * 16 + dl;
                float dc = sqi[tr][rg] + sqj[tc] - acc[tr][tc][rg] * (1.0f / 196.0f);
                if (gi == gj) dc = 0.f;
                dc = fmaxf(dc, 0.f) + 1e-5f;
                float val = __expf(0.4f * __logf(dc));
                rs[tr][rg] += val;
                cs[tc] += val;
                if (gj >= gi)
                    adc[gi * (769 - gi) / 2 + (gj - gi)] = val;
            }
        }
    }
    #pragma unroll
    for (int tr = 0; tr < 4; ++tr)
        #pragma unroll
        for (int rg = 0; rg < 4; ++rg) {
            float vv = rs[tr][rg];
            vv += __shfl_xor(vv, 1); vv += __shfl_xor(vv, 2);
            vv += __shfl_xor(vv, 4); vv += __shfl_xor(vv, 8);
            rs[tr][rg] = vv;
        }
    if ((lane & 15) == 0) {
        #pragma unroll
        for (int tr = 0; tr < 4; ++tr)
            #pragma unroll
            for (int rg = 0; rg < 4; ++rg)
                atomicAdd(&ws[WS_RSUM + b * DIM + rbase + tr * 16 + ms4 * 4 + rg],
                          rs[tr][rg]);
    }
    if (ti != tj) {
        #pragma unroll
        for (int tc = 0; tc < 4; ++tc) {
            float vv = cs[tc];
            vv += __shfl_xor(vv, 16); vv += __shfl_xor(vv, 32);
            cs[tc] = vv;
        }
        if (lane < 16) {
            #pragma unroll
            for (int tc = 0; tc < 4; ++tc)
                atomicAdd(&ws[WS_RSUM + b * DIM + cbase + tc * 16 + lane], cs[tc]);
        }
    }
}

// k3: row means + grand mean
__global__ __launch_bounds__(384) void k_rowmean(float* __restrict__ ws) {
    int b = blockIdx.x, i = threadIdx.x;
    float s = ws[WS_RSUM + b * DIM + i];
    ws[WS_RM + b * DIM + i] = s * (1.0f / 384.0f);
    __shared__ float red[6];
    float tsum = wave_reduce(s);
    int lane = i & 63, wv = i >> 6;
    if (!lane) red[wv] = tsum;
    __syncthreads();
    if (i == 0) {
        float tot = red[0]+red[1]+red[2]+red[3]+red[4]+red[5];
        ws[WS_GM + b] = tot * (1.0f / (384.0f * 384.0f));
    }
}

// k4: in-place centering of adc (fp32), row-walk, + qnorm^2 partials
__global__ __launch_bounds__(256) void k_center(float* __restrict__ ws,
                                                float* __restrict__ out) {
    int s = blockIdx.x;       // row class i % 4 (load balance)
    int b = blockIdx.y;
    int tid = threadIdx.x;
    __shared__ float rmL[DIM];
    __shared__ float redL[4];
    const float* rm = ws + WS_RM + b * DIM;
    rmL[tid] = rm[tid];
    if (tid < DIM - 256) rmL[256 + tid] = rm[256 + tid];
    float gm = ws[WS_GM + b];
    __syncthreads();
    float* adc = out + OUT_ADC + (size_t)b * RTRI;
    float acc = 0.f;
    for (int i = s; i < DIM; i += 4) {
        int base = i * (769 - i) / 2;
        int L = DIM - i;
        float rmi = rmL[i] - gm;
        for (int off = tid; off < L; off += 256) {
            float v = adc[base + off];
            float nv = v - rmi - rmL[i + off];
            adc[base + off] = nv;
            acc = fmaf(nv, nv, acc);
        }
    }
    float t = wave_reduce(acc);
    if (!(tid & 63)) redL[tid >> 6] = t;
    __syncthreads();
    if (!tid) ws[WS_QPART + b * 8 + s] = redL[0] + redL[1] + redL[2] + redL[3];
}

// k5: DOTS[r][c] = dot(query r, ctx c) via split-K bf16 MFMA.
// grid (2,2,NS2): 104x104 output quadrant (padded 128x128), 8 waves (2x4).
#define DKD 32              // K per step
#define LDK 40              // LDS stride in bf16 (80 B: 2-way max aliasing)
#define NS2 105
#define CHB 22              // chunks per block: 105*22*32 = 73920
__global__ __launch_bounds__(512) void k_dots(const float* __restrict__ out,
                                              float* __restrict__ ws) {
    int qi = blockIdx.x, qj = blockIdx.y, ns = blockIdx.z;
    int tid = threadIdx.x;
    int lane = tid & 63, w = tid >> 6;
    int wr = w >> 2, wc = w & 3;        // 2x4 waves: 64 rows x 32 cols each
    __shared__ __align__(16) unsigned short As[128 * LDK];
    __shared__ __align__(16) unsigned short Bs[128 * LDK];
    const float* adc = out + OUT_ADC;
    int realA = (qi == 0) ? 104 : 96;
    int realB = (qj == 0) ? 104 : 96;
    const float* qb = adc + (size_t)(NSUP + qi * 104) * RTRI;
    const float* cb = adc + (size_t)(qj * 104) * RTRI;

    f32x4 acc[4][2] = {};
    for (int ck = 0; ck < CHB; ++ck) {
        int k0 = (ns * CHB + ck) * DKD;
        #pragma unroll
        for (int it = 0; it < 4; ++it) {
            int idx = tid + it * 512;
            int arr = idx >> 10;
            int r = (idx >> 3) & 127;
            int kq = (idx & 7) << 2;
            const float* src = arr ? cb : qb;
            int real = arr ? realB : realA;
            float4 v = make_float4(0.f, 0.f, 0.f, 0.f);
            if (r < real) v = *(const float4*)&src[(size_t)r * RTRI + k0 + kq];
            short4v sv;
            sv[0] = (short)f2bf(v.x); sv[1] = (short)f2bf(v.y);
            sv[2] = (short)f2bf(v.z); sv[3] = (short)f2bf(v.w);
            unsigned short* dst = arr ? Bs : As;
            *(short4v*)&dst[r * LDK + kq] = sv;
        }
        __syncthreads();
        int kb = (lane >> 4) * 8;
        bf16x8 af[4], bfv[2];
        #pragma unroll
        for (int tr = 0; tr < 4; ++tr)
            af[tr] = *(const bf16x8*)&As[(wr * 64 + tr * 16 + (lane & 15)) * LDK + kb];
        #pragma unroll
        for (int tc = 0; tc < 2; ++tc)
            bfv[tc] = *(const bf16x8*)&Bs[(wc * 32 + tc * 16 + (lane & 15)) * LDK + kb];
        #pragma unroll
        for (int tr = 0; tr < 4; ++tr)
            #pragma unroll
            for (int tc = 0; tc < 2; ++tc)
                acc[tr][tc] = __builtin_amdgcn_mfma_f32_16x16x32_bf16(
                    af[tr], bfv[tc], acc[tr][tc], 0, 0, 0);
        __syncthreads();
    }
    #pragma unroll
    for (int tr = 0; tr < 4; ++tr)
        #pragma unroll
        for (int tc = 0; tc < 2; ++tc)
            #pragma unroll
            for (int rg = 0; rg < 4; ++rg) {
                int lr = wr * 64 + tr * 16 + (lane >> 4) * 4 + rg;
                int lc = wc * 32 + tc * 16 + (lane & 15);
                if (lr < realA && lc < realB)
                    atomicAdd(&ws[WS_DOTS + (qi * 104 + lr) * 200 + (qj * 104 + lc)],
                              acc[tr][tc][rg]);
            }
}

// k5b: partial within-class ctx pair dots -> PNP[o][15], split-K
__global__ __launch_bounds__(256) void k_pn(const int* __restrict__ labels,
                                            const float* __restrict__ out,
                                            float* __restrict__ ws) {
    int o = blockIdx.x;      // c*8+f
    int sp = blockIdx.y;     // 0..7 K split
    int c = o >> 3, f = o & 7;
    int tid = threadIdx.x;
    __shared__ int rows[5];
    if (tid == 0) {
        int cnt = 0;
        for (int s = 0; s < 25; s++)
            if (labels[s] == c && cnt < 5) rows[cnt++] = s * 8 + f;
    }
    __syncthreads();
    const float* adc = out + OUT_ADC;
    float acc[15] = {};
    int lo = sp * 9240, hi = lo + 9240;
    for (int k = lo + tid; k < hi; k += 256) {
        float v[5];
        #pragma unroll
        for (int a = 0; a < 5; a++) v[a] = adc[(size_t)rows[a] * RTRI + k];
        int idx = 0;
        #pragma unroll
        for (int a = 0; a < 5; a++)
            #pragma unroll
            for (int b2 = a; b2 < 5; b2++) {
                acc[idx] = fmaf(v[a], v[b2], acc[idx]);
                idx++;
            }
    }
    __shared__ float red[15];
    if (tid < 15) red[tid] = 0.f;
    __syncthreads();
    #pragma unroll
    for (int i = 0; i < 15; i++) {
        float t = wave_reduce(acc[i]);
        if (!(tid & 63)) atomicAdd(&red[i], t);
    }
    __syncthreads();
    if (tid < 15) atomicAdd(&ws[WS_PNP + o * 16 + tid], red[tid]);
}

// k6: qn + pn finalize + ad from DOTS/PNP/QPART
__global__ __launch_bounds__(256) void k_post(const int* __restrict__ labels,
                                              float* __restrict__ ws) {
    __shared__ int mem[5][5];
    int tid = threadIdx.x;
    if (tid == 0) {
        int cnt[5] = {0,0,0,0,0};
        for (int s = 0; s < 25; s++) { int c = labels[s]; if (cnt[c] < 5) mem[c][cnt[c]++] = s; }
    }
    __syncthreads();
    for (int r = tid; r < 200; r += 256) {
        float ssum = 0.f;
        #pragma unroll
        for (int k = 0; k < 8; k++) ssum += ws[WS_QPART + (200 + r) * 8 + k];
        ws[WS_QN + r] = fmaxf(sqrtf(fmaxf(ssum, 0.f)), 1e-8f);
    }
    if (tid < 40) {
        float tot = 0.f;
        int idx = 0;
        #pragma unroll
        for (int a = 0; a < 5; a++)
            #pragma unroll
            for (int b2 = a; b2 < 5; b2++) {
                tot += ((a == b2) ? 1.f : 2.f) * ws[WS_PNP + tid * 16 + idx];
                idx++;
            }
        ws[WS_PN + tid] = fmaxf(sqrtf(fmaxf(tot, 0.f)) * 0.2f, 1e-8f);
    }
    __syncthreads();
    for (int idx = tid; idx < 8000; idx += 256) {
        int r = idx / 40, o = idx % 40;
        int c = o >> 3, f = o & 7;
        float s = 0.f;
        #pragma unroll
        for (int a = 0; a < 5; a++)
            s += ws[WS_DOTS + r * 200 + mem[c][a] * 8 + f];
        ws[WS_AD + idx] = s * 0.2f;
    }
}

// k7: proto[q] = mean_f(query cls) + mean_all(support cls)
__global__ __launch_bounds__(384) void k_proto(const float* __restrict__ lsn,
                                               float* __restrict__ ws) {
    int tid = threadIdx.x;
    float tsv = 0.f;
    for (int r = 0; r < 200; r++) tsv += lsn[(size_t)r * 197 * DIM + tid];
    tsv *= (1.0f / 200.0f);
    for (int q = 0; q < 25; q++) {
        float s = 0.f;
        #pragma unroll
        for (int f = 0; f < 8; f++) s += lsn[(size_t)(200 + q * 8 + f) * 197 * DIM + tid];
        ws[WS_PROTO + q * DIM + tid] = s * (1.0f / 8.0f) + tsv;
    }
}

// k8: tsm[q][g] = proto[q] . gen_weight[g]
__global__ __launch_bounds__(64) void k_tsm(const float* __restrict__ gw,
                                            float* __restrict__ ws) {
    int q = blockIdx.x, g = threadIdx.x;
    const float* pr = ws + WS_PROTO + q * DIM;
    const float* gr = gw + g * DIM;
    float s = 0.f;
    for (int d = 0; d < DIM; d++) s = fmaf(pr[d], gr[d], s);
    ws[WS_TSM + q * 64 + g] = s;
}

// k9: final score
__global__ __launch_bounds__(128) void k_score(const float* __restrict__ ws,
                                               float* __restrict__ out) {
    int t = threadIdx.x;
    if (t >= 125) return;
    int q = t / 5, wway = t % 5;
    float s = 0.f;
    for (int f = 0; f < 8; f++) {
        float qn = ws[WS_QN + q * 8 + f];
        for (int g = 0; g < 8; g++) {
            float ad = ws[WS_AD + (q * 8 + f) * 40 + wway * 8 + g];
            float pnv = ws[WS_PN + wway * 8 + g];
            s += (ad / (qn * pnv)) * ws[WS_TSM + q * 64 + f * 8 + g];
        }
    }
    out[OUT_SCORE + t] = s;
}

extern "C" void kernel_launch(void* const* d_in, const int* in_sizes, int n_in,
                              void* d_out, int out_size, void* d_ws, size_t ws_size,
                              hipStream_t stream) {
    const float* lsn = (const float*)d_in[0];
    const float* gw = (const float*)d_in[1];
    const int* labels = (const int*)d_in[2];
    float* ws = (float*)d_ws;
    float* out = (float*)d_out;

    {
        int n = (WS_AD - WS_RSUM);   // RSUM, RM, GM, QPART, DOTS, PNP
        k_zero<<<dim3((n + 255) / 256), dim3(256), 0, stream>>>(ws + WS_RSUM, n);
    }
    k_prep<<<dim3(BATCH), dim3(384), 0, stream>>>(lsn, ws, out);
    k_gram<<<dim3(6, BATCH), dim3(256), 0, stream>>>(lsn, ws, out);
    k_rowmean<<<dim3(BATCH), dim3(384), 0, stream>>>(ws);
    k_center<<<dim3(4, BATCH), dim3(256), 0, stream>>>(ws, out);
    k_dots<<<dim3(2, 2, NS2), dim3(512), 0, stream>>>(out, ws);
    k_pn<<<dim3(40, 8), dim3(256), 0, stream>>>(labels, out, ws);
    k_post<<<1, dim3(256), 0, stream>>>(labels, ws);
    k_proto<<<1, dim3(384), 0, stream>>>(lsn, ws);
    k_tsm<<<dim3(25), dim3(64), 0, stream>>>(gw, ws);
    k_score<<<1, dim3(128), 0, stream>>>(ws, out);
}